// Round 1
// baseline (977.548 us; speedup 1.0000x reference)
//
#include <hip/hip_runtime.h>
#include <math.h>

#define BATCH 2
#define SEQ 2048
#define HID 2048
#define NS 16
#define RANK 64
#define NCHUNK 64
#define CLEN 32   // SEQ / NCHUNK

static_assert(SEQ == NCHUNK * CLEN, "chunking must cover SEQ");

// ---------------------------------------------------------------------------
// Kernel 1: per (b,s) row, compute dt_low[64] = input_row . W_dt_in^T,
//           Bm[16] = input_row . W_B^T, Cm[16] = input_row . W_C^T
// One block per row; input row staged in LDS.
// ---------------------------------------------------------------------------
__global__ __launch_bounds__(256) void k_proj_in(
    const float* __restrict__ input,
    const float* __restrict__ W_dt_in,   // [RANK, HID]
    const float* __restrict__ W_B,       // [NS, HID]
    const float* __restrict__ W_C,       // [NS, HID]
    float* __restrict__ dt_low,          // [B*S, RANK]
    float* __restrict__ Bm,              // [B*S, NS]
    float* __restrict__ Cm)              // [B*S, NS]
{
    __shared__ float row[HID];
    __shared__ float red[256];
    const int bs  = blockIdx.x;
    const int tid = threadIdx.x;
    const float* in_row = input + (size_t)bs * HID;
    for (int i = tid * 4; i < HID; i += 256 * 4)
        *(float4*)(row + i) = *(const float4*)(in_row + i);
    __syncthreads();

    // ---- dt_low: 64 outputs, 4 partial segments of 512 each ----
    {
        const int o = tid & 63;
        const int q = tid >> 6;   // 0..3
        const float* w = W_dt_in + (size_t)o * HID + q * 512;
        const float* r = row + q * 512;
        float acc = 0.f;
        #pragma unroll 4
        for (int i = 0; i < 512; i += 4) {
            float4 wv = *(const float4*)(w + i);
            float4 rv = *(const float4*)(r + i);
            acc = fmaf(wv.x, rv.x, acc);
            acc = fmaf(wv.y, rv.y, acc);
            acc = fmaf(wv.z, rv.z, acc);
            acc = fmaf(wv.w, rv.w, acc);
        }
        red[tid] = acc;
        __syncthreads();
        if (tid < 64)
            dt_low[(size_t)bs * RANK + tid] =
                red[tid] + red[tid + 64] + red[tid + 128] + red[tid + 192];
        __syncthreads();
    }

    // ---- Bm/Cm: 32 outputs, 8 partial segments of 256 each ----
    {
        const int o   = tid & 31;
        const int seg = tid >> 5;  // 0..7
        const int n   = o & 15;
        const float* wbase = (o < 16) ? W_B : W_C;
        const float* w = wbase + (size_t)n * HID + seg * 256;
        const float* r = row + seg * 256;
        float acc = 0.f;
        #pragma unroll 4
        for (int i = 0; i < 256; i += 4) {
            float4 wv = *(const float4*)(w + i);
            float4 rv = *(const float4*)(r + i);
            acc = fmaf(wv.x, rv.x, acc);
            acc = fmaf(wv.y, rv.y, acc);
            acc = fmaf(wv.z, rv.z, acc);
            acc = fmaf(wv.w, rv.w, acc);
        }
        red[tid] = acc;
        __syncthreads();
        if (tid < 32) {
            float s = 0.f;
            #pragma unroll
            for (int k = 0; k < 8; k++) s += red[tid + 32 * k];
            if (tid < 16) Bm[(size_t)bs * NS + tid] = s;
            else          Cm[(size_t)bs * NS + (tid - 16)] = s;
        }
    }
}

// ---------------------------------------------------------------------------
// Kernel 2: dt[b,s,h] = softplus(dt_low_row . W_dt_out[h,:] + b_dt_out[h])
// One block per (b,s) row; dt_low row (64 floats) staged in LDS.
// ---------------------------------------------------------------------------
__global__ __launch_bounds__(256) void k_dt_out(
    const float* __restrict__ dt_low,    // [B*S, RANK]
    const float* __restrict__ W_dt_out,  // [HID, RANK]
    const float* __restrict__ b_dt_out,  // [HID]
    float* __restrict__ dt)              // [B*S, HID]
{
    __shared__ float low[RANK];
    const int bs  = blockIdx.x;
    const int tid = threadIdx.x;
    if (tid < RANK) low[tid] = dt_low[(size_t)bs * RANK + tid];
    __syncthreads();
    #pragma unroll
    for (int k = 0; k < HID / 256; k++) {
        const int h = tid + 256 * k;
        const float* w = W_dt_out + (size_t)h * RANK;
        float acc = b_dt_out[h];
        #pragma unroll
        for (int i = 0; i < RANK; i += 4) {
            float4 wv = *(const float4*)(w + i);
            acc = fmaf(wv.x, low[i], acc);
            acc = fmaf(wv.y, low[i + 1], acc);
            acc = fmaf(wv.z, low[i + 2], acc);
            acc = fmaf(wv.w, low[i + 3], acc);
        }
        // softplus(x) = max(x,0) + log1p(exp(-|x|))  (matches jax.nn.softplus)
        const float sp = fmaxf(acc, 0.f) + log1pf(expf(-fabsf(acc)));
        dt[(size_t)bs * HID + h] = sp;
    }
}

// ---------------------------------------------------------------------------
// Chunked scan. Lane = one (b, h, chunk); state x[NS] in registers.
// Pass A: local scan from zero; record P = prod(a) and X = final local state.
// ---------------------------------------------------------------------------
__global__ __launch_bounds__(256) void k_scan_local(
    const float* __restrict__ input,
    const float* __restrict__ dt,
    const float* __restrict__ Bm,
    const float* __restrict__ A_log,    // [HID, NS]
    float* __restrict__ Pws,            // [NCHUNK, BATCH, HID, NS]
    float* __restrict__ Xws)            // [NCHUNK, BATCH, HID, NS]
{
    const int gid = blockIdx.x * 256 + threadIdx.x;
    const int h  = gid & (HID - 1);
    const int bc = gid >> 11;           // log2(HID) = 11
    const int c  = bc & (NCHUNK - 1);
    const int b  = bc >> 6;             // log2(NCHUNK) = 6

    float A[NS];
    {
        const float* al = A_log + (size_t)h * NS;
        #pragma unroll
        for (int n = 0; n < NS; n++) A[n] = -__expf(al[n]);
    }
    float x[NS], P[NS];
    #pragma unroll
    for (int n = 0; n < NS; n++) { x[n] = 0.f; P[n] = 1.f; }

    const int s0 = c * CLEN;
    for (int s = s0; s < s0 + CLEN; s++) {
        const size_t rowoff = (size_t)b * SEQ + s;
        const float dtv = dt[rowoff * HID + h];
        const float u   = input[rowoff * HID + h];
        const float bu  = dtv * u;
        float Bv[NS];
        {
            const float4* bp = (const float4*)(Bm + rowoff * NS);
            *(float4*)(Bv + 0)  = bp[0];
            *(float4*)(Bv + 4)  = bp[1];
            *(float4*)(Bv + 8)  = bp[2];
            *(float4*)(Bv + 12) = bp[3];
        }
        #pragma unroll
        for (int n = 0; n < NS; n++) {
            const float a = __expf(A[n] * dtv);
            P[n] *= a;
            x[n] = fmaf(a, x[n], bu * Bv[n]);
        }
    }
    float* pp = Pws + (((size_t)c * BATCH + b) * HID + h) * NS;
    float* xp = Xws + (((size_t)c * BATCH + b) * HID + h) * NS;
    #pragma unroll
    for (int n = 0; n < NS; n += 4) {
        *(float4*)(pp + n) = make_float4(P[n], P[n + 1], P[n + 2], P[n + 3]);
        *(float4*)(xp + n) = make_float4(x[n], x[n + 1], x[n + 2], x[n + 3]);
    }
}

// ---------------------------------------------------------------------------
// Pass B: per (b,h), sequentially combine chunk summaries.
// Overwrites Pws[c] with the true initial state entering chunk c.
// ---------------------------------------------------------------------------
__global__ __launch_bounds__(256) void k_scan_combine(
    float* __restrict__ Pws,            // in: P products; out: initial states
    const float* __restrict__ Xws)
{
    const int gid = blockIdx.x * 256 + threadIdx.x;  // B*HID threads
    const int h = gid & (HID - 1);
    const int b = gid >> 11;
    float xi[NS];
    #pragma unroll
    for (int n = 0; n < NS; n++) xi[n] = 0.f;
    for (int c = 0; c < NCHUNK; c++) {
        float* pp = Pws + (((size_t)c * BATCH + b) * HID + h) * NS;
        const float* xp = Xws + (((size_t)c * BATCH + b) * HID + h) * NS;
        float P[NS], X[NS];
        #pragma unroll
        for (int n = 0; n < NS; n += 4) {
            *(float4*)(P + n) = *(const float4*)(pp + n);
            *(float4*)(X + n) = *(const float4*)(xp + n);
        }
        #pragma unroll
        for (int n = 0; n < NS; n += 4)
            *(float4*)(pp + n) = make_float4(xi[n], xi[n + 1], xi[n + 2], xi[n + 3]);
        #pragma unroll
        for (int n = 0; n < NS; n++)
            xi[n] = fmaf(P[n], xi[n], X[n]);
    }
}

// ---------------------------------------------------------------------------
// Pass C: replay each chunk from its true initial state, emit y.
// ---------------------------------------------------------------------------
__global__ __launch_bounds__(256) void k_scan_final(
    const float* __restrict__ input,
    const float* __restrict__ dt,
    const float* __restrict__ Bm,
    const float* __restrict__ Cm,
    const float* __restrict__ A_log,
    const float* __restrict__ Dv,       // [HID]
    const float* __restrict__ Iws,      // initial states (aliased Pws)
    float* __restrict__ out)            // [B, S, HID]
{
    const int gid = blockIdx.x * 256 + threadIdx.x;
    const int h  = gid & (HID - 1);
    const int bc = gid >> 11;
    const int c  = bc & (NCHUNK - 1);
    const int b  = bc >> 6;

    float A[NS];
    {
        const float* al = A_log + (size_t)h * NS;
        #pragma unroll
        for (int n = 0; n < NS; n++) A[n] = -__expf(al[n]);
    }
    float x[NS];
    {
        const float* ip = Iws + (((size_t)c * BATCH + b) * HID + h) * NS;
        #pragma unroll
        for (int n = 0; n < NS; n += 4)
            *(float4*)(x + n) = *(const float4*)(ip + n);
    }
    const float Dh = Dv[h];

    const int s0 = c * CLEN;
    for (int s = s0; s < s0 + CLEN; s++) {
        const size_t rowoff = (size_t)b * SEQ + s;
        const float dtv = dt[rowoff * HID + h];
        const float u   = input[rowoff * HID + h];
        const float bu  = dtv * u;
        float Bv[NS], Cv[NS];
        {
            const float4* bp = (const float4*)(Bm + rowoff * NS);
            const float4* cp = (const float4*)(Cm + rowoff * NS);
            *(float4*)(Bv + 0)  = bp[0];
            *(float4*)(Bv + 4)  = bp[1];
            *(float4*)(Bv + 8)  = bp[2];
            *(float4*)(Bv + 12) = bp[3];
            *(float4*)(Cv + 0)  = cp[0];
            *(float4*)(Cv + 4)  = cp[1];
            *(float4*)(Cv + 8)  = cp[2];
            *(float4*)(Cv + 12) = cp[3];
        }
        float y = Dh * u;
        #pragma unroll
        for (int n = 0; n < NS; n++) {
            const float a = __expf(A[n] * dtv);
            x[n] = fmaf(a, x[n], bu * Bv[n]);
            y = fmaf(Cv[n], x[n], y);
        }
        out[rowoff * HID + h] = y;
    }
}

// ---------------------------------------------------------------------------
extern "C" void kernel_launch(void* const* d_in, const int* in_sizes, int n_in,
                              void* d_out, int out_size, void* d_ws, size_t ws_size,
                              hipStream_t stream)
{
    const float* input    = (const float*)d_in[0];
    const float* W_dt_in  = (const float*)d_in[1];
    const float* W_dt_out = (const float*)d_in[2];
    const float* b_dt_out = (const float*)d_in[3];
    const float* W_B      = (const float*)d_in[4];
    const float* W_C      = (const float*)d_in[5];
    const float* Dv       = (const float*)d_in[6];
    const float* A_log    = (const float*)d_in[7];
    float* out = (float*)d_out;

    float* ws = (float*)d_ws;
    size_t off = 0;
    float* dt     = ws + off; off += (size_t)BATCH * SEQ * HID;         // 33.5 MB
    float* dt_low = ws + off; off += (size_t)BATCH * SEQ * RANK;        //  1.0 MB
    float* Bm     = ws + off; off += (size_t)BATCH * SEQ * NS;          //  0.25 MB
    float* Cm     = ws + off; off += (size_t)BATCH * SEQ * NS;          //  0.25 MB
    float* Pws    = ws + off; off += (size_t)BATCH * HID * NCHUNK * NS; // 16.8 MB
    float* Xws    = ws + off; off += (size_t)BATCH * HID * NCHUNK * NS; // 16.8 MB
    // total ~68.7 MB of d_ws

    k_proj_in<<<BATCH * SEQ, 256, 0, stream>>>(input, W_dt_in, W_B, W_C,
                                               dt_low, Bm, Cm);
    k_dt_out<<<BATCH * SEQ, 256, 0, stream>>>(dt_low, W_dt_out, b_dt_out, dt);
    k_scan_local<<<(BATCH * HID * NCHUNK) / 256, 256, 0, stream>>>(
        input, dt, Bm, A_log, Pws, Xws);
    k_scan_combine<<<(BATCH * HID) / 256, 256, 0, stream>>>(Pws, Xws);
    k_scan_final<<<(BATCH * HID * NCHUNK) / 256, 256, 0, stream>>>(
        input, dt, Bm, Cm, A_log, Dv, Pws, out);
}

// Round 2
// 312.766 us; speedup vs baseline: 3.1255x; 3.1255x over previous
//
#include <hip/hip_runtime.h>
#include <math.h>

#define BATCH 2
#define SEQ 2048
#define HID 2048
#define NS 16
#define RANK 64
#define NCHUNK 64
#define CLEN 32   // SEQ / NCHUNK
#define ROWS (BATCH * SEQ)   // 4096
#define NOUT 96              // RANK + NS + NS
#define KCH 8                // split-K chunks for GEMM1
#define KC (HID / KCH)       // 256 K per chunk
#define LDW 68               // padded LDS row stride (64 + 4, keeps 16B align)

static_assert(SEQ == NCHUNK * CLEN, "chunking must cover SEQ");

// ---------------------------------------------------------------------------
// GEMM1 (split-K partial): P96[c, bs, j] = sum_{k in chunk c} input[bs,k]*W[j,k]
// where W rows 0..63 = W_dt_in, 64..79 = W_B, 80..95 = W_C.
// Block: 64 rows x 96 outs, K-chunk 256 processed in 64-wide LDS tiles.
// Thread tile: 6 outs x 4 rows.
// ---------------------------------------------------------------------------
__global__ __launch_bounds__(256) void k_proj_in2(
    const float* __restrict__ input,
    const float* __restrict__ W_dt_in,
    const float* __restrict__ W_B,
    const float* __restrict__ W_C,
    float* __restrict__ P96)            // [KCH, ROWS, NOUT]
{
    __shared__ float lin[64 * LDW];     // 17.4 KB
    __shared__ float lw[NOUT * LDW];    // 26.1 KB
    const int tid = threadIdx.x;
    const int R0 = blockIdx.x * 64;
    const int kbase = blockIdx.y * KC;
    const int og = tid & 15;            // out-group 0..15
    const int rg = tid >> 4;            // row-group 0..15

    float acc[6][4];
    #pragma unroll
    for (int j = 0; j < 6; j++)
        #pragma unroll
        for (int i = 0; i < 4; i++) acc[j][i] = 0.f;

    for (int kt = 0; kt < KC / 64; kt++) {
        const int k0 = kbase + kt * 64;
        __syncthreads();
        // stage input tile 64 rows x 64 k (coalesced float4)
        #pragma unroll
        for (int l = 0; l < 4; l++) {
            const int idx = tid + 256 * l;
            const int rl = idx >> 4, kq = idx & 15;
            *(float4*)(lin + rl * LDW + kq * 4) =
                *(const float4*)(input + (size_t)(R0 + rl) * HID + k0 + kq * 4);
        }
        // stage W tile 96 rows x 64 k
        #pragma unroll
        for (int l = 0; l < 6; l++) {
            const int idx = tid + 256 * l;
            const int jl = idx >> 4, kq = idx & 15;
            const float* src = (jl < RANK) ? (W_dt_in + (size_t)jl * HID)
                             : (jl < RANK + NS) ? (W_B + (size_t)(jl - RANK) * HID)
                             : (W_C + (size_t)(jl - RANK - NS) * HID);
            *(float4*)(lw + jl * LDW + kq * 4) = *(const float4*)(src + k0 + kq * 4);
        }
        __syncthreads();
        #pragma unroll
        for (int kq = 0; kq < 16; kq++) {
            float4 iv[4], wv[6];
            #pragma unroll
            for (int i = 0; i < 4; i++)
                iv[i] = *(const float4*)(lin + (rg + 16 * i) * LDW + kq * 4);
            #pragma unroll
            for (int j = 0; j < 6; j++)
                wv[j] = *(const float4*)(lw + (og + 16 * j) * LDW + kq * 4);
            #pragma unroll
            for (int j = 0; j < 6; j++)
                #pragma unroll
                for (int i = 0; i < 4; i++) {
                    acc[j][i] = fmaf(wv[j].x, iv[i].x, acc[j][i]);
                    acc[j][i] = fmaf(wv[j].y, iv[i].y, acc[j][i]);
                    acc[j][i] = fmaf(wv[j].z, iv[i].z, acc[j][i]);
                    acc[j][i] = fmaf(wv[j].w, iv[i].w, acc[j][i]);
                }
        }
    }
    float* dst = P96 + (size_t)blockIdx.y * ROWS * NOUT;
    #pragma unroll
    for (int j = 0; j < 6; j++)
        #pragma unroll
        for (int i = 0; i < 4; i++)
            dst[(size_t)(R0 + rg + 16 * i) * NOUT + og + 16 * j] = acc[j][i];
}

// ---------------------------------------------------------------------------
// Reduce split-K partials into dt_low / Bm / Cm.
// ---------------------------------------------------------------------------
__global__ __launch_bounds__(256) void k_reduce96(
    const float* __restrict__ P96,
    float* __restrict__ dt_low,
    float* __restrict__ Bm,
    float* __restrict__ Cm)
{
    const int gid = blockIdx.x * 256 + threadIdx.x;  // ROWS*NOUT threads
    const int bs = gid / NOUT;
    const int j  = gid - bs * NOUT;
    float s = 0.f;
    #pragma unroll
    for (int c = 0; c < KCH; c++)
        s += P96[(size_t)c * ROWS * NOUT + gid];
    if (j < RANK)           dt_low[(size_t)bs * RANK + j] = s;
    else if (j < RANK + NS) Bm[(size_t)bs * NS + (j - RANK)] = s;
    else                    Cm[(size_t)bs * NS + (j - RANK - NS)] = s;
}

// ---------------------------------------------------------------------------
// GEMM2: dt[bs,h] = softplus(dt_low[bs,:] . W2[h,:] + bias[h]).
// Block: 64 rows x 128 h, K = 64 in one LDS tile. Thread tile: 4 h x 8 rows.
// ---------------------------------------------------------------------------
__global__ __launch_bounds__(256) void k_dt_out2(
    const float* __restrict__ dt_low,   // [ROWS, RANK]
    const float* __restrict__ W2,       // [HID, RANK]
    const float* __restrict__ bias,     // [HID]
    float* __restrict__ dt)             // [ROWS, HID]
{
    __shared__ float lw[128 * LDW];     // 34.8 KB
    __shared__ float ll[64 * LDW];      // 17.4 KB
    const int tid = threadIdx.x;
    const int tx = tid & 31, ty = tid >> 5;   // tx: h lane, ty: row lane 0..7
    const int H0 = blockIdx.x * 128;
    const int R0 = blockIdx.y * 64;

    #pragma unroll
    for (int l = 0; l < 8; l++) {
        const int idx = tid + 256 * l;
        const int hl = idx >> 4, kq = idx & 15;
        *(float4*)(lw + hl * LDW + kq * 4) =
            *(const float4*)(W2 + (size_t)(H0 + hl) * RANK + kq * 4);
    }
    #pragma unroll
    for (int l = 0; l < 4; l++) {
        const int idx = tid + 256 * l;
        const int rl = idx >> 4, kq = idx & 15;
        *(float4*)(ll + rl * LDW + kq * 4) =
            *(const float4*)(dt_low + (size_t)(R0 + rl) * RANK + kq * 4);
    }
    __syncthreads();

    float acc[4][8];
    #pragma unroll
    for (int j = 0; j < 4; j++)
        #pragma unroll
        for (int i = 0; i < 8; i++) acc[j][i] = 0.f;

    #pragma unroll
    for (int kq = 0; kq < 16; kq++) {
        float4 wv[4], lv[8];
        #pragma unroll
        for (int j = 0; j < 4; j++)
            wv[j] = *(const float4*)(lw + (tx + 32 * j) * LDW + kq * 4);
        #pragma unroll
        for (int i = 0; i < 8; i++)
            lv[i] = *(const float4*)(ll + (ty + 8 * i) * LDW + kq * 4);
        #pragma unroll
        for (int j = 0; j < 4; j++)
            #pragma unroll
            for (int i = 0; i < 8; i++) {
                acc[j][i] = fmaf(wv[j].x, lv[i].x, acc[j][i]);
                acc[j][i] = fmaf(wv[j].y, lv[i].y, acc[j][i]);
                acc[j][i] = fmaf(wv[j].z, lv[i].z, acc[j][i]);
                acc[j][i] = fmaf(wv[j].w, lv[i].w, acc[j][i]);
            }
    }

    #pragma unroll
    for (int j = 0; j < 4; j++) {
        const int h = H0 + tx + 32 * j;
        const float bj = bias[h];
        #pragma unroll
        for (int i = 0; i < 8; i++) {
            const int r = R0 + ty + 8 * i;
            const float v = acc[j][i] + bj;
            // softplus(x) = max(x,0) + log1p(exp(-|x|))
            const float sp = fmaxf(v, 0.f) + log1pf(expf(-fabsf(v)));
            dt[(size_t)r * HID + h] = sp;
        }
    }
}

// ---------------------------------------------------------------------------
// Chunked scan. Lane = one (b, h, chunk); state x[NS] in registers.
// Pass A: local scan from zero; record P = prod(a) and X = final local state.
// ---------------------------------------------------------------------------
__global__ __launch_bounds__(256) void k_scan_local(
    const float* __restrict__ input,
    const float* __restrict__ dt,
    const float* __restrict__ Bm,
    const float* __restrict__ A_log,    // [HID, NS]
    float* __restrict__ Pws,            // [NCHUNK, BATCH, HID, NS]
    float* __restrict__ Xws)            // [NCHUNK, BATCH, HID, NS]
{
    const int gid = blockIdx.x * 256 + threadIdx.x;
    const int h  = gid & (HID - 1);
    const int bc = gid >> 11;           // log2(HID) = 11
    const int c  = bc & (NCHUNK - 1);
    const int b  = bc >> 6;             // log2(NCHUNK) = 6

    float A[NS];
    {
        const float* al = A_log + (size_t)h * NS;
        #pragma unroll
        for (int n = 0; n < NS; n++) A[n] = -__expf(al[n]);
    }
    float x[NS], P[NS];
    #pragma unroll
    for (int n = 0; n < NS; n++) { x[n] = 0.f; P[n] = 1.f; }

    const int s0 = c * CLEN;
    for (int s = s0; s < s0 + CLEN; s++) {
        const size_t rowoff = (size_t)b * SEQ + s;
        const float dtv = dt[rowoff * HID + h];
        const float u   = input[rowoff * HID + h];
        const float bu  = dtv * u;
        float Bv[NS];
        {
            const float4* bp = (const float4*)(Bm + rowoff * NS);
            *(float4*)(Bv + 0)  = bp[0];
            *(float4*)(Bv + 4)  = bp[1];
            *(float4*)(Bv + 8)  = bp[2];
            *(float4*)(Bv + 12) = bp[3];
        }
        #pragma unroll
        for (int n = 0; n < NS; n++) {
            const float a = __expf(A[n] * dtv);
            P[n] *= a;
            x[n] = fmaf(a, x[n], bu * Bv[n]);
        }
    }
    float* pp = Pws + (((size_t)c * BATCH + b) * HID + h) * NS;
    float* xp = Xws + (((size_t)c * BATCH + b) * HID + h) * NS;
    #pragma unroll
    for (int n = 0; n < NS; n += 4) {
        *(float4*)(pp + n) = make_float4(P[n], P[n + 1], P[n + 2], P[n + 3]);
        *(float4*)(xp + n) = make_float4(x[n], x[n + 1], x[n + 2], x[n + 3]);
    }
}

// ---------------------------------------------------------------------------
// Pass B: per (b,h), sequentially combine chunk summaries.
// Overwrites Pws[c] with the true initial state entering chunk c.
// ---------------------------------------------------------------------------
__global__ __launch_bounds__(256) void k_scan_combine(
    float* __restrict__ Pws,            // in: P products; out: initial states
    const float* __restrict__ Xws)
{
    const int gid = blockIdx.x * 256 + threadIdx.x;  // B*HID threads
    const int h = gid & (HID - 1);
    const int b = gid >> 11;
    float xi[NS];
    #pragma unroll
    for (int n = 0; n < NS; n++) xi[n] = 0.f;
    for (int c = 0; c < NCHUNK; c++) {
        float* pp = Pws + (((size_t)c * BATCH + b) * HID + h) * NS;
        const float* xp = Xws + (((size_t)c * BATCH + b) * HID + h) * NS;
        float P[NS], X[NS];
        #pragma unroll
        for (int n = 0; n < NS; n += 4) {
            *(float4*)(P + n) = *(const float4*)(pp + n);
            *(float4*)(X + n) = *(const float4*)(xp + n);
        }
        #pragma unroll
        for (int n = 0; n < NS; n += 4)
            *(float4*)(pp + n) = make_float4(xi[n], xi[n + 1], xi[n + 2], xi[n + 3]);
        #pragma unroll
        for (int n = 0; n < NS; n++)
            xi[n] = fmaf(P[n], xi[n], X[n]);
    }
}

// ---------------------------------------------------------------------------
// Pass C: replay each chunk from its true initial state, emit y.
// ---------------------------------------------------------------------------
__global__ __launch_bounds__(256) void k_scan_final(
    const float* __restrict__ input,
    const float* __restrict__ dt,
    const float* __restrict__ Bm,
    const float* __restrict__ Cm,
    const float* __restrict__ A_log,
    const float* __restrict__ Dv,       // [HID]
    const float* __restrict__ Iws,      // initial states (aliased Pws)
    float* __restrict__ out)            // [B, S, HID]
{
    const int gid = blockIdx.x * 256 + threadIdx.x;
    const int h  = gid & (HID - 1);
    const int bc = gid >> 11;
    const int c  = bc & (NCHUNK - 1);
    const int b  = bc >> 6;

    float A[NS];
    {
        const float* al = A_log + (size_t)h * NS;
        #pragma unroll
        for (int n = 0; n < NS; n++) A[n] = -__expf(al[n]);
    }
    float x[NS];
    {
        const float* ip = Iws + (((size_t)c * BATCH + b) * HID + h) * NS;
        #pragma unroll
        for (int n = 0; n < NS; n += 4)
            *(float4*)(x + n) = *(const float4*)(ip + n);
    }
    const float Dh = Dv[h];

    const int s0 = c * CLEN;
    for (int s = s0; s < s0 + CLEN; s++) {
        const size_t rowoff = (size_t)b * SEQ + s;
        const float dtv = dt[rowoff * HID + h];
        const float u   = input[rowoff * HID + h];
        const float bu  = dtv * u;
        float Bv[NS], Cv[NS];
        {
            const float4* bp = (const float4*)(Bm + rowoff * NS);
            const float4* cp = (const float4*)(Cm + rowoff * NS);
            *(float4*)(Bv + 0)  = bp[0];
            *(float4*)(Bv + 4)  = bp[1];
            *(float4*)(Bv + 8)  = bp[2];
            *(float4*)(Bv + 12) = bp[3];
            *(float4*)(Cv + 0)  = cp[0];
            *(float4*)(Cv + 4)  = cp[1];
            *(float4*)(Cv + 8)  = cp[2];
            *(float4*)(Cv + 12) = cp[3];
        }
        float y = Dh * u;
        #pragma unroll
        for (int n = 0; n < NS; n++) {
            const float a = __expf(A[n] * dtv);
            x[n] = fmaf(a, x[n], bu * Bv[n]);
            y = fmaf(Cv[n], x[n], y);
        }
        out[rowoff * HID + h] = y;
    }
}

// ---------------------------------------------------------------------------
extern "C" void kernel_launch(void* const* d_in, const int* in_sizes, int n_in,
                              void* d_out, int out_size, void* d_ws, size_t ws_size,
                              hipStream_t stream)
{
    const float* input    = (const float*)d_in[0];
    const float* W_dt_in  = (const float*)d_in[1];
    const float* W_dt_out = (const float*)d_in[2];
    const float* b_dt_out = (const float*)d_in[3];
    const float* W_B      = (const float*)d_in[4];
    const float* W_C      = (const float*)d_in[5];
    const float* Dv       = (const float*)d_in[6];
    const float* A_log    = (const float*)d_in[7];
    float* out = (float*)d_out;

    float* ws = (float*)d_ws;
    size_t off = 0;
    float* dt     = ws + off; off += (size_t)ROWS * HID;                // 33.5 MB
    float* dt_low = ws + off; off += (size_t)ROWS * RANK;               //  1.0 MB
    float* Bm     = ws + off; off += (size_t)ROWS * NS;                 //  0.25 MB
    float* Cm     = ws + off; off += (size_t)ROWS * NS;                 //  0.25 MB
    float* Pws    = ws + off; off += (size_t)BATCH * HID * NCHUNK * NS; // 16.8 MB
    float* Xws    = ws + off; off += (size_t)BATCH * HID * NCHUNK * NS; // 16.8 MB
    float* P96    = ws + off; off += (size_t)KCH * ROWS * NOUT;         // 12.6 MB
    // total ~81 MB of d_ws

    k_proj_in2<<<dim3(ROWS / 64, KCH), 256, 0, stream>>>(
        input, W_dt_in, W_B, W_C, P96);
    k_reduce96<<<(ROWS * NOUT) / 256, 256, 0, stream>>>(P96, dt_low, Bm, Cm);
    k_dt_out2<<<dim3(HID / 128, ROWS / 64), 256, 0, stream>>>(
        dt_low, W_dt_out, b_dt_out, dt);
    k_scan_local<<<(BATCH * HID * NCHUNK) / 256, 256, 0, stream>>>(
        input, dt, Bm, A_log, Pws, Xws);
    k_scan_combine<<<(BATCH * HID) / 256, 256, 0, stream>>>(Pws, Xws);
    k_scan_final<<<(BATCH * HID * NCHUNK) / 256, 256, 0, stream>>>(
        input, dt, Bm, Cm, A_log, Dv, Pws, out);
}

// Round 3
// 245.770 us; speedup vs baseline: 3.9775x; 1.2726x over previous
//
#include <hip/hip_runtime.h>
#include <math.h>

#define BATCH 2
#define SEQ 2048
#define HID 2048
#define NS 16
#define RANK 64
#define NCHUNK 64
#define CLEN 32   // SEQ / NCHUNK
#define ROWS (BATCH * SEQ)   // 4096
#define NOUT 96              // RANK + NS + NS
#define KCH 8                // split-K chunks for GEMM1
#define KC (HID / KCH)       // 256 K per chunk
#define LDW 68               // padded LDS row stride (64 + 4, keeps 16B align)

static_assert(SEQ == NCHUNK * CLEN, "chunking must cover SEQ");

// ---------------------------------------------------------------------------
// GEMM1 (split-K partial): P96[c, bs, j] = sum_{k in chunk c} input[bs,k]*W[j,k]
// where W rows 0..63 = W_dt_in, 64..79 = W_B, 80..95 = W_C.
// Block: 64 rows x 96 outs, K-chunk 256 processed in 64-wide LDS tiles.
// Thread tile: 6 outs x 4 rows.
// ---------------------------------------------------------------------------
__global__ __launch_bounds__(256) void k_proj_in2(
    const float* __restrict__ input,
    const float* __restrict__ W_dt_in,
    const float* __restrict__ W_B,
    const float* __restrict__ W_C,
    float* __restrict__ P96)            // [KCH, ROWS, NOUT]
{
    __shared__ float lin[64 * LDW];     // 17.4 KB
    __shared__ float lw[NOUT * LDW];    // 26.1 KB
    const int tid = threadIdx.x;
    const int R0 = blockIdx.x * 64;
    const int kbase = blockIdx.y * KC;
    const int og = tid & 15;            // out-group 0..15
    const int rg = tid >> 4;            // row-group 0..15

    float acc[6][4];
    #pragma unroll
    for (int j = 0; j < 6; j++)
        #pragma unroll
        for (int i = 0; i < 4; i++) acc[j][i] = 0.f;

    for (int kt = 0; kt < KC / 64; kt++) {
        const int k0 = kbase + kt * 64;
        __syncthreads();
        // stage input tile 64 rows x 64 k (coalesced float4)
        #pragma unroll
        for (int l = 0; l < 4; l++) {
            const int idx = tid + 256 * l;
            const int rl = idx >> 4, kq = idx & 15;
            *(float4*)(lin + rl * LDW + kq * 4) =
                *(const float4*)(input + (size_t)(R0 + rl) * HID + k0 + kq * 4);
        }
        // stage W tile 96 rows x 64 k
        #pragma unroll
        for (int l = 0; l < 6; l++) {
            const int idx = tid + 256 * l;
            const int jl = idx >> 4, kq = idx & 15;
            const float* src = (jl < RANK) ? (W_dt_in + (size_t)jl * HID)
                             : (jl < RANK + NS) ? (W_B + (size_t)(jl - RANK) * HID)
                             : (W_C + (size_t)(jl - RANK - NS) * HID);
            *(float4*)(lw + jl * LDW + kq * 4) = *(const float4*)(src + k0 + kq * 4);
        }
        __syncthreads();
        #pragma unroll
        for (int kq = 0; kq < 16; kq++) {
            float4 iv[4], wv[6];
            #pragma unroll
            for (int i = 0; i < 4; i++)
                iv[i] = *(const float4*)(lin + (rg + 16 * i) * LDW + kq * 4);
            #pragma unroll
            for (int j = 0; j < 6; j++)
                wv[j] = *(const float4*)(lw + (og + 16 * j) * LDW + kq * 4);
            #pragma unroll
            for (int j = 0; j < 6; j++)
                #pragma unroll
                for (int i = 0; i < 4; i++) {
                    acc[j][i] = fmaf(wv[j].x, iv[i].x, acc[j][i]);
                    acc[j][i] = fmaf(wv[j].y, iv[i].y, acc[j][i]);
                    acc[j][i] = fmaf(wv[j].z, iv[i].z, acc[j][i]);
                    acc[j][i] = fmaf(wv[j].w, iv[i].w, acc[j][i]);
                }
        }
    }
    float* dst = P96 + (size_t)blockIdx.y * ROWS * NOUT;
    #pragma unroll
    for (int j = 0; j < 6; j++)
        #pragma unroll
        for (int i = 0; i < 4; i++)
            dst[(size_t)(R0 + rg + 16 * i) * NOUT + og + 16 * j] = acc[j][i];
}

// ---------------------------------------------------------------------------
// Reduce split-K partials into dt_low / Bm / Cm.
// ---------------------------------------------------------------------------
__global__ __launch_bounds__(256) void k_reduce96(
    const float* __restrict__ P96,
    float* __restrict__ dt_low,
    float* __restrict__ Bm,
    float* __restrict__ Cm)
{
    const int gid = blockIdx.x * 256 + threadIdx.x;  // ROWS*NOUT threads
    const int bs = gid / NOUT;
    const int j  = gid - bs * NOUT;
    float s = 0.f;
    #pragma unroll
    for (int c = 0; c < KCH; c++)
        s += P96[(size_t)c * ROWS * NOUT + gid];
    if (j < RANK)           dt_low[(size_t)bs * RANK + j] = s;
    else if (j < RANK + NS) Bm[(size_t)bs * NS + (j - RANK)] = s;
    else                    Cm[(size_t)bs * NS + (j - RANK - NS)] = s;
}

// ---------------------------------------------------------------------------
// GEMM2: dt[bs,h] = softplus(dt_low[bs,:] . W2[h,:] + bias[h]).
// Block: 64 rows x 128 h, K = 64 in one LDS tile. Thread tile: 4 h x 8 rows.
// ---------------------------------------------------------------------------
__global__ __launch_bounds__(256) void k_dt_out2(
    const float* __restrict__ dt_low,   // [ROWS, RANK]
    const float* __restrict__ W2,       // [HID, RANK]
    const float* __restrict__ bias,     // [HID]
    float* __restrict__ dt)             // [ROWS, HID]
{
    __shared__ float lw[128 * LDW];     // 34.8 KB
    __shared__ float ll[64 * LDW];      // 17.4 KB
    const int tid = threadIdx.x;
    const int tx = tid & 31, ty = tid >> 5;   // tx: h lane, ty: row lane 0..7
    const int H0 = blockIdx.x * 128;
    const int R0 = blockIdx.y * 64;

    #pragma unroll
    for (int l = 0; l < 8; l++) {
        const int idx = tid + 256 * l;
        const int hl = idx >> 4, kq = idx & 15;
        *(float4*)(lw + hl * LDW + kq * 4) =
            *(const float4*)(W2 + (size_t)(H0 + hl) * RANK + kq * 4);
    }
    #pragma unroll
    for (int l = 0; l < 4; l++) {
        const int idx = tid + 256 * l;
        const int rl = idx >> 4, kq = idx & 15;
        *(float4*)(ll + rl * LDW + kq * 4) =
            *(const float4*)(dt_low + (size_t)(R0 + rl) * RANK + kq * 4);
    }
    __syncthreads();

    float acc[4][8];
    #pragma unroll
    for (int j = 0; j < 4; j++)
        #pragma unroll
        for (int i = 0; i < 8; i++) acc[j][i] = 0.f;

    #pragma unroll
    for (int kq = 0; kq < 16; kq++) {
        float4 wv[4], lv[8];
        #pragma unroll
        for (int j = 0; j < 4; j++)
            wv[j] = *(const float4*)(lw + (tx + 32 * j) * LDW + kq * 4);
        #pragma unroll
        for (int i = 0; i < 8; i++)
            lv[i] = *(const float4*)(ll + (ty + 8 * i) * LDW + kq * 4);
        #pragma unroll
        for (int j = 0; j < 4; j++)
            #pragma unroll
            for (int i = 0; i < 8; i++) {
                acc[j][i] = fmaf(wv[j].x, lv[i].x, acc[j][i]);
                acc[j][i] = fmaf(wv[j].y, lv[i].y, acc[j][i]);
                acc[j][i] = fmaf(wv[j].z, lv[i].z, acc[j][i]);
                acc[j][i] = fmaf(wv[j].w, lv[i].w, acc[j][i]);
            }
    }

    #pragma unroll
    for (int j = 0; j < 4; j++) {
        const int h = H0 + tx + 32 * j;
        const float bj = bias[h];
        #pragma unroll
        for (int i = 0; i < 8; i++) {
            const int r = R0 + ty + 8 * i;
            const float v = acc[j][i] + bj;
            // softplus(x) = max(x,0) + log1p(exp(-|x|))
            const float sp = fmaxf(v, 0.f) + log1pf(expf(-fabsf(v)));
            dt[(size_t)r * HID + h] = sp;
        }
    }
}

// ---------------------------------------------------------------------------
// Chunked scan. Lane = one (b, h, chunk); state x[NS] in registers.
// Pass A: local scan from zero; record P = prod(a) and X = final local state.
// ---------------------------------------------------------------------------
__global__ __launch_bounds__(256) void k_scan_local(
    const float* __restrict__ input,
    const float* __restrict__ dt,
    const float* __restrict__ Bm,
    const float* __restrict__ A_log,    // [HID, NS]
    float* __restrict__ Pws,            // [NCHUNK, BATCH, HID, NS]
    float* __restrict__ Xws)            // [NCHUNK, BATCH, HID, NS]
{
    const int gid = blockIdx.x * 256 + threadIdx.x;
    const int h  = gid & (HID - 1);
    const int bc = gid >> 11;           // log2(HID) = 11
    const int c  = bc & (NCHUNK - 1);
    const int b  = bc >> 6;             // log2(NCHUNK) = 6

    float A[NS];
    {
        const float* al = A_log + (size_t)h * NS;
        #pragma unroll
        for (int n = 0; n < NS; n++) A[n] = -__expf(al[n]);
    }
    float x[NS], P[NS];
    #pragma unroll
    for (int n = 0; n < NS; n++) { x[n] = 0.f; P[n] = 1.f; }

    const int s0 = c * CLEN;
    for (int s = s0; s < s0 + CLEN; s++) {
        const size_t rowoff = (size_t)b * SEQ + s;
        const float dtv = dt[rowoff * HID + h];
        const float u   = input[rowoff * HID + h];
        const float bu  = dtv * u;
        float Bv[NS];
        {
            const float4* bp = (const float4*)(Bm + rowoff * NS);
            *(float4*)(Bv + 0)  = bp[0];
            *(float4*)(Bv + 4)  = bp[1];
            *(float4*)(Bv + 8)  = bp[2];
            *(float4*)(Bv + 12) = bp[3];
        }
        #pragma unroll
        for (int n = 0; n < NS; n++) {
            const float a = __expf(A[n] * dtv);
            P[n] *= a;
            x[n] = fmaf(a, x[n], bu * Bv[n]);
        }
    }
    float* pp = Pws + (((size_t)c * BATCH + b) * HID + h) * NS;
    float* xp = Xws + (((size_t)c * BATCH + b) * HID + h) * NS;
    #pragma unroll
    for (int n = 0; n < NS; n += 4) {
        *(float4*)(pp + n) = make_float4(P[n], P[n + 1], P[n + 2], P[n + 3]);
        *(float4*)(xp + n) = make_float4(x[n], x[n + 1], x[n + 2], x[n + 3]);
    }
}

// ---------------------------------------------------------------------------
// Pass B: one thread per (b,h,n) scalar recurrence over chunks.
// Overwrites Pws[c] with the true initial state entering chunk c.
// Chunk-groups of 8 -> 16 outstanding coalesced loads per iteration.
// ---------------------------------------------------------------------------
__global__ __launch_bounds__(256) void k_scan_combine(
    float* __restrict__ Pws,            // in: P products; out: initial states
    const float* __restrict__ Xws)
{
    const int gid = blockIdx.x * 256 + threadIdx.x;  // BATCH*HID*NS threads
    const size_t stride = (size_t)BATCH * HID * NS;  // chunk plane
    float* pp = Pws + gid;
    const float* xp = Xws + gid;
    float xi = 0.f;
    #pragma unroll
    for (int cg = 0; cg < NCHUNK / 8; cg++) {
        float P[8], X[8], init[8];
        #pragma unroll
        for (int i = 0; i < 8; i++) {
            P[i] = pp[(cg * 8 + i) * stride];
            X[i] = xp[(cg * 8 + i) * stride];
        }
        #pragma unroll
        for (int i = 0; i < 8; i++) {
            init[i] = xi;
            xi = fmaf(P[i], xi, X[i]);
        }
        #pragma unroll
        for (int i = 0; i < 8; i++)
            pp[(cg * 8 + i) * stride] = init[i];
    }
}

// ---------------------------------------------------------------------------
// Pass C: replay each chunk from its true initial state, emit y.
// ---------------------------------------------------------------------------
__global__ __launch_bounds__(256) void k_scan_final(
    const float* __restrict__ input,
    const float* __restrict__ dt,
    const float* __restrict__ Bm,
    const float* __restrict__ Cm,
    const float* __restrict__ A_log,
    const float* __restrict__ Dv,       // [HID]
    const float* __restrict__ Iws,      // initial states (aliased Pws)
    float* __restrict__ out)            // [B, S, HID]
{
    const int gid = blockIdx.x * 256 + threadIdx.x;
    const int h  = gid & (HID - 1);
    const int bc = gid >> 11;
    const int c  = bc & (NCHUNK - 1);
    const int b  = bc >> 6;

    float A[NS];
    {
        const float* al = A_log + (size_t)h * NS;
        #pragma unroll
        for (int n = 0; n < NS; n++) A[n] = -__expf(al[n]);
    }
    float x[NS];
    {
        const float* ip = Iws + (((size_t)c * BATCH + b) * HID + h) * NS;
        #pragma unroll
        for (int n = 0; n < NS; n += 4)
            *(float4*)(x + n) = *(const float4*)(ip + n);
    }
    const float Dh = Dv[h];

    const int s0 = c * CLEN;
    for (int s = s0; s < s0 + CLEN; s++) {
        const size_t rowoff = (size_t)b * SEQ + s;
        const float dtv = dt[rowoff * HID + h];
        const float u   = input[rowoff * HID + h];
        const float bu  = dtv * u;
        float Bv[NS], Cv[NS];
        {
            const float4* bp = (const float4*)(Bm + rowoff * NS);
            const float4* cp = (const float4*)(Cm + rowoff * NS);
            *(float4*)(Bv + 0)  = bp[0];
            *(float4*)(Bv + 4)  = bp[1];
            *(float4*)(Bv + 8)  = bp[2];
            *(float4*)(Bv + 12) = bp[3];
            *(float4*)(Cv + 0)  = cp[0];
            *(float4*)(Cv + 4)  = cp[1];
            *(float4*)(Cv + 8)  = cp[2];
            *(float4*)(Cv + 12) = cp[3];
        }
        float y = Dh * u;
        #pragma unroll
        for (int n = 0; n < NS; n++) {
            const float a = __expf(A[n] * dtv);
            x[n] = fmaf(a, x[n], bu * Bv[n]);
            y = fmaf(Cv[n], x[n], y);
        }
        out[rowoff * HID + h] = y;
    }
}

// ---------------------------------------------------------------------------
extern "C" void kernel_launch(void* const* d_in, const int* in_sizes, int n_in,
                              void* d_out, int out_size, void* d_ws, size_t ws_size,
                              hipStream_t stream)
{
    const float* input    = (const float*)d_in[0];
    const float* W_dt_in  = (const float*)d_in[1];
    const float* W_dt_out = (const float*)d_in[2];
    const float* b_dt_out = (const float*)d_in[3];
    const float* W_B      = (const float*)d_in[4];
    const float* W_C      = (const float*)d_in[5];
    const float* Dv       = (const float*)d_in[6];
    const float* A_log    = (const float*)d_in[7];
    float* out = (float*)d_out;

    float* ws = (float*)d_ws;
    size_t off = 0;
    float* dt     = ws + off; off += (size_t)ROWS * HID;                // 33.5 MB
    float* dt_low = ws + off; off += (size_t)ROWS * RANK;               //  1.0 MB
    float* Bm     = ws + off; off += (size_t)ROWS * NS;                 //  0.25 MB
    float* Cm     = ws + off; off += (size_t)ROWS * NS;                 //  0.25 MB
    float* Pws    = ws + off; off += (size_t)BATCH * HID * NCHUNK * NS; // 16.8 MB
    float* Xws    = ws + off; off += (size_t)BATCH * HID * NCHUNK * NS; // 16.8 MB
    float* P96    = ws + off; off += (size_t)KCH * ROWS * NOUT;         // 12.6 MB
    // total ~81 MB of d_ws

    k_proj_in2<<<dim3(ROWS / 64, KCH), 256, 0, stream>>>(
        input, W_dt_in, W_B, W_C, P96);
    k_reduce96<<<(ROWS * NOUT) / 256, 256, 0, stream>>>(P96, dt_low, Bm, Cm);
    k_dt_out2<<<dim3(HID / 128, ROWS / 64), 256, 0, stream>>>(
        dt_low, W_dt_out, b_dt_out, dt);
    k_scan_local<<<(BATCH * HID * NCHUNK) / 256, 256, 0, stream>>>(
        input, dt, Bm, A_log, Pws, Xws);
    k_scan_combine<<<(BATCH * HID * NS) / 256, 256, 0, stream>>>(Pws, Xws);
    k_scan_final<<<(BATCH * HID * NCHUNK) / 256, 256, 0, stream>>>(
        input, dt, Bm, Cm, A_log, Dv, Pws, out);
}